// Round 6
// baseline (173.696 us; speedup 1.0000x reference)
//
#include <hip/hip_runtime.h>

#define B_ 4
#define C_ 256
#define CQK 64
#define N_ 4096
#define SEG 2
#define SEGN (N_ / SEG)    // 2048
#define NB 128
#define ITERS (SEGN / NB)  // 16
#define TS 512             // elements per 16x32 fragment tile (1 KB)

typedef _Float16 f16;
typedef __attribute__((ext_vector_type(8))) _Float16 f16x8;
typedef __attribute__((ext_vector_type(4))) _Float16 f16x4;
typedef __attribute__((ext_vector_type(4))) float f32x4;
typedef __attribute__((ext_vector_type(4))) float float4v;

// Fragment-tiled layouts: matrix [R][K] stored as [R/16][K/32] tiles of
// [16][32] f16; wave fragment load = 64 lanes x 16 B over one 1 KB tile.
#define TILE_OFF(l15, quad) ((l15) * 32 + (quad) * 8)

// Inline fp32 weight row fragment -> f16x8 (replaces prep_w kernel; weights
// stay L2-resident fp32, per-fragment conversion is ~8 cvt VALU ops).
__device__ __forceinline__ f16x8 load_wfrag(const float* __restrict__ Ws,
                                            int row, int col) {
  const float* p = Ws + (size_t)row * C_ + col;
  float4v a = *(const float4v*)p;
  float4v b = *(const float4v*)(p + 4);
  f16x8 r;
#pragma unroll
  for (int j = 0; j < 4; j++) { r[j] = (f16)a[j]; r[4 + j] = (f16)b[j]; }
  return r;
}

// ---------------- K1: fused transpose + Q/K/V projection (v2) ---------------
// grid: (N/32, B) = 512 blocks, 256 thr (4 waves) => 2 blocks/CU so the
// mem-bound transpose phase of one block overlaps the MFMA phase of the other
// (v1 was 256 blocks = 1/CU, fully phase-serialized). x loaded as float4
// along n (1 KB/instruction; v1 used scalar fp32 = 256 B/instr). Weights are
// converted inline from fp32 (prep_w kernel eliminated).
__global__ __launch_bounds__(256) void proj(
    const float* __restrict__ x, const float* __restrict__ wq,
    const float* __restrict__ wk, const float* __restrict__ wv,
    const float* __restrict__ bq, const float* __restrict__ bk,
    const float* __restrict__ bv, f16* __restrict__ QTt, f16* __restrict__ KTt,
    f16* __restrict__ Vt) {
  __shared__ float xs[32][65];    // fp32 transpose stage (32n x 64c chunk)
  __shared__ f16 xt[2 * 8 * TS];  // x strip tiled: [nt 2][kt 8][16 n][32 c]
  int n0 = blockIdx.x * 32;
  int b = blockIdx.y;
  int tid = threadIdx.x, lane = tid & 63, w = tid >> 6;  // w 0..3
  int l15 = lane & 15, quad = lane >> 4;
  const float* xb = x + (size_t)b * C_ * N_;

  for (int cc = 0; cc < 4; cc++) {
    // A1/A2: load 64c x 32n as float4 along n, store transposed to xs
#pragma unroll
    for (int k = 0; k < 2; k++) {
      int p = w * 2 + k;                  // instruction index 0..7
      int c_off = p * 8 + (lane >> 3);    // 0..63
      int n4 = (lane & 7) * 4;            // 0..28
      float4v f4 = *(const float4v*)(xb + (size_t)(cc * 64 + c_off) * N_ + n0 + n4);
#pragma unroll
      for (int j = 0; j < 4; j++) xs[n4 + j][c_off] = f4[j];
    }
    __syncthreads();
    // A3: repack to f16 fragment tiles: wave task (nt = w>>1, half = w&1)
    {
      int nt = w >> 1;
      f16x8 v;
#pragma unroll
      for (int j = 0; j < 8; j++)
        v[j] = (f16)xs[nt * 16 + l15][32 * (w & 1) + quad * 8 + j];
      *(f16x8*)(xt + (nt * 8 + cc * 2 + (w & 1)) * TS + l15 * 32 + quad * 8) = v;
    }
    __syncthreads();
  }

  f32x4 acc[6][2];  // [task j][nt]
#pragma unroll
  for (int j = 0; j < 6; j++)
#pragma unroll
    for (int nt = 0; nt < 2; nt++) acc[j][nt] = (f32x4){0.f, 0.f, 0.f, 0.f};

#pragma unroll
  for (int kt = 0; kt < 8; kt++) {
    f16x8 xf[2];
#pragma unroll
    for (int nt = 0; nt < 2; nt++)
      xf[nt] = *(const f16x8*)(xt + (nt * 8 + kt) * TS + TILE_OFF(l15, quad));
#pragma unroll
    for (int j = 0; j < 6; j++) {
      int g = w * 6 + j;  // wave-uniform, 0..23
      const float* Ws;
      int ot;
      bool isV = g < 16;
      if (isV) { Ws = wv; ot = g; }
      else if (g < 20) { Ws = wq; ot = g - 16; }
      else { Ws = wk; ot = g - 20; }
      f16x8 wf = load_wfrag(Ws, ot * 16 + l15, kt * 32 + quad * 8);
#pragma unroll
      for (int nt = 0; nt < 2; nt++)
        acc[j][nt] = isV
            ? __builtin_amdgcn_mfma_f32_16x16x32_f16(xf[nt], wf, acc[j][nt], 0, 0, 0)
            : __builtin_amdgcn_mfma_f32_16x16x32_f16(wf, xf[nt], acc[j][nt], 0, 0, 0);
    }
  }

  f16* vbout = Vt + (size_t)b * C_ * N_;
#pragma unroll
  for (int j = 0; j < 6; j++) {
    int g = w * 6 + j;
    if (g < 16) {
      float bvv = bv[16 * g + l15];
#pragma unroll
      for (int nt = 0; nt < 2; nt++) {
        f16x4 vals;
#pragma unroll
        for (int r = 0; r < 4; r++) vals[r] = (f16)(acc[j][nt][r] + bvv);
        *(f16x4*)(vbout + ((size_t)g * 128 + (n0 >> 5)) * TS +
                  l15 * 32 + 16 * nt + 4 * quad) = vals;
      }
    } else {
      int oq = (g < 20) ? (g - 16) : (g - 20);
      const float* bias = (g < 20) ? bq : bk;
      f16* ob = ((g < 20) ? QTt : KTt) + (size_t)b * N_ * CQK;
#pragma unroll
      for (int nt = 0; nt < 2; nt++) {
        f16x4 vals;
#pragma unroll
        for (int r = 0; r < 4; r++)
          vals[r] = (f16)(acc[j][nt][r] + bias[16 * oq + 4 * quad + r]);
        *(f16x4*)(ob + (((size_t)(n0 >> 4) + nt) * 2 + (oq >> 1)) * TS + l15 * 32 +
                  16 * (oq & 1) + 4 * quad) = vals;
      }
    }
  }
}

// ---------------- K2: fused attention + wg proj (r5 pipelined core) ---------
// grid: (8, 64). blockIdx.x = seg*4+b (XCD-pinned via %8), 4 waves.
// Body identical to r5 (best attn so far, 62.7us). Only change: wg epilogue
// converts fp32 weights inline (prep_w eliminated); same RTN cast semantics.
__global__ __launch_bounds__(256, 2) void attn(const f16* __restrict__ qt,
                                               const f16* __restrict__ kt,
                                               const f16* __restrict__ v,
                                               const float* __restrict__ wg,
                                               f16* __restrict__ part) {
  __shared__ __align__(16) f16 sPt[2][64][128];  // P^T dbuf (32 KB); reused as O buf
  int sb = blockIdx.x;
  int seg = sb >> 2;
  int b = sb & 3;
  int m0 = blockIdx.y * 64;
  int tid = threadIdx.x, lane = tid & 63, w = tid >> 6;
  int l15 = lane & 15, quad = lane >> 4;
  const f16* qtb = qt + (size_t)b * N_ * CQK;
  const f16* ktb = kt + (size_t)b * N_ * CQK;
  const f16* vb = v + (size_t)b * C_ * N_;

  f32x4 oacc[4][4];
#pragma unroll
  for (int ct = 0; ct < 4; ct++)
#pragma unroll
    for (int mt = 0; mt < 4; mt++) oacc[ct][mt] = (f32x4){0.f, 0.f, 0.f, 0.f};

  f16x8 kf[4][2];
#pragma unroll
  for (int mt = 0; mt < 4; mt++)
#pragma unroll
    for (int ks = 0; ks < 2; ks++)
      kf[mt][ks] = *(const f16x8*)(ktb + ((size_t)((m0 >> 4) + mt) * 2 + ks) * TS +
                                   TILE_OFF(l15, quad));

  f16x8 qf[2][2];
#pragma unroll
  for (int nt = 0; nt < 2; nt++)
#pragma unroll
    for (int ks = 0; ks < 2; ks++)
      qf[nt][ks] = *(const f16x8*)(qtb +
                                   ((size_t)(((seg * SEGN) >> 4) + 2 * w + nt) * 2 + ks) * TS +
                                   TILE_OFF(l15, quad));

  // ---- prologue: QK(0) -> sPt[0] ----
  {
    char* buf = (char*)sPt[0];
#pragma unroll
    for (int nt = 0; nt < 2; nt++) {
      f32x4 sacc[4];
#pragma unroll
      for (int mt = 0; mt < 4; mt++) sacc[mt] = (f32x4){0.f, 0.f, 0.f, 0.f};
#pragma unroll
      for (int ks = 0; ks < 2; ks++)
#pragma unroll
        for (int mt = 0; mt < 4; mt++)
          sacc[mt] = __builtin_amdgcn_mfma_f32_16x16x32_f16(qf[nt][ks], kf[mt][ks],
                                                            sacc[mt], 0, 0, 0);
#pragma unroll
      for (int mt = 0; mt < 4; mt++) {
        f16x4 p;
#pragma unroll
        for (int r = 0; r < 4; r++) {
          float s = sacc[mt][r];
          p[r] = (f16)(s > 0.0f ? s : (__expf(s) - 1.0f));
        }
        int row = 16 * mt + l15;
        int colb = (64 * w + 32 * nt + 8 * quad) ^ ((row & 7) << 4);
        *(f16x4*)(buf + row * 256 + colb) = p;
      }
    }
  }
  // prefetch qf for it=1 (used by QK(1) inside iter 0)
  {
    int nq = seg * SEGN + NB;
#pragma unroll
    for (int nt = 0; nt < 2; nt++)
#pragma unroll
      for (int ks = 0; ks < 2; ks++)
        qf[nt][ks] = *(const f16x8*)(qtb +
                                     ((size_t)((nq >> 4) + 2 * w + nt) * 2 + ks) * TS +
                                     TILE_OFF(l15, quad));
  }
  __syncthreads();

  for (int it = 0; it < ITERS; it++) {
    int n0 = seg * SEGN + it * NB;
    char* rbuf = (char*)sPt[it & 1];        // P(it), read by PV
    char* wbuf = (char*)sPt[(it + 1) & 1];  // P(it+1), written by QK
    bool hasNext = (it + 1 < ITERS);

    f16x8 vfA[2][4];
#pragma unroll
    for (int ks = 0; ks < 2; ks++)
#pragma unroll
      for (int ct = 0; ct < 4; ct++)
        vfA[ks][ct] = *(const f16x8*)(vb +
                                      ((size_t)(4 * w + ct) * 128 + (n0 >> 5) + ks) * TS +
                                      TILE_OFF(l15, quad));

    // QK(it+1) nt=0 accumulate (interleaves with PV phase 0 below)
    f32x4 s0[4], s1[4];
    if (hasNext) {
#pragma unroll
      for (int mt = 0; mt < 4; mt++) s0[mt] = (f32x4){0.f, 0.f, 0.f, 0.f};
#pragma unroll
      for (int ks = 0; ks < 2; ks++)
#pragma unroll
        for (int mt = 0; mt < 4; mt++)
          s0[mt] = __builtin_amdgcn_mfma_f32_16x16x32_f16(qf[0][ks], kf[mt][ks],
                                                          s0[mt], 0, 0, 0);
    }

    f16x8 pa[4];
#pragma unroll
    for (int mt = 0; mt < 4; mt++) {
      int row = 16 * mt + l15;
      pa[mt] = *(const f16x8*)(rbuf + row * 256 + ((quad * 16) ^ ((row & 7) << 4)));
    }
#pragma unroll
    for (int ct = 0; ct < 4; ct++)
#pragma unroll
      for (int mt = 0; mt < 4; mt++)
        oacc[ct][mt] = __builtin_amdgcn_mfma_f32_16x16x32_f16(vfA[0][ct], pa[mt],
                                                              oacc[ct][mt], 0, 0, 0);

    f16x8 vfB[2][4];
#pragma unroll
    for (int ks = 0; ks < 2; ks++)
#pragma unroll
      for (int ct = 0; ct < 4; ct++)
        vfB[ks][ct] = *(const f16x8*)(vb + ((size_t)(4 * w + ct) * 128 + (n0 >> 5) +
                                            2 + ks) * TS +
                                      TILE_OFF(l15, quad));

    // elu+pack+write for nt=0 (VALU; interleaves with PV MFMA around it)
    if (hasNext) {
#pragma unroll
      for (int mt = 0; mt < 4; mt++) {
        f16x4 p;
#pragma unroll
        for (int r = 0; r < 4; r++) {
          float s = s0[mt][r];
          p[r] = (f16)(s > 0.0f ? s : (__expf(s) - 1.0f));
        }
        int row = 16 * mt + l15;
        int colb = (64 * w + 8 * quad) ^ ((row & 7) << 4);
        *(f16x4*)(wbuf + row * 256 + colb) = p;
      }
    }

#pragma unroll
    for (int mt = 0; mt < 4; mt++) {
      int row = 16 * mt + l15;
      pa[mt] = *(const f16x8*)(rbuf + row * 256 + ((64 + quad * 16) ^ ((row & 7) << 4)));
    }
#pragma unroll
    for (int ct = 0; ct < 4; ct++)
#pragma unroll
      for (int mt = 0; mt < 4; mt++)
        oacc[ct][mt] = __builtin_amdgcn_mfma_f32_16x16x32_f16(vfA[1][ct], pa[mt],
                                                              oacc[ct][mt], 0, 0, 0);

    // QK(it+1) nt=1 accumulate
    if (hasNext) {
#pragma unroll
      for (int mt = 0; mt < 4; mt++) s1[mt] = (f32x4){0.f, 0.f, 0.f, 0.f};
#pragma unroll
      for (int ks = 0; ks < 2; ks++)
#pragma unroll
        for (int mt = 0; mt < 4; mt++)
          s1[mt] = __builtin_amdgcn_mfma_f32_16x16x32_f16(qf[1][ks], kf[mt][ks],
                                                          s1[mt], 0, 0, 0);
    }

#pragma unroll
    for (int mt = 0; mt < 4; mt++) {
      int row = 16 * mt + l15;
      pa[mt] = *(const f16x8*)(rbuf + row * 256 + ((128 + quad * 16) ^ ((row & 7) << 4)));
    }
#pragma unroll
    for (int ct = 0; ct < 4; ct++)
#pragma unroll
      for (int mt = 0; mt < 4; mt++)
        oacc[ct][mt] = __builtin_amdgcn_mfma_f32_16x16x32_f16(vfB[0][ct], pa[mt],
                                                              oacc[ct][mt], 0, 0, 0);

    // elu+pack+write for nt=1, then qf prefetch for it+2
    if (hasNext) {
#pragma unroll
      for (int mt = 0; mt < 4; mt++) {
        f16x4 p;
#pragma unroll
        for (int r = 0; r < 4; r++) {
          float s = s1[mt][r];
          p[r] = (f16)(s > 0.0f ? s : (__expf(s) - 1.0f));
        }
        int row = 16 * mt + l15;
        int colb = (64 * w + 32 + 8 * quad) ^ ((row & 7) << 4);
        *(f16x4*)(wbuf + row * 256 + colb) = p;
      }
      if (it + 2 < ITERS) {
        int nq = seg * SEGN + (it + 2) * NB;
#pragma unroll
        for (int nt = 0; nt < 2; nt++)
#pragma unroll
          for (int ks = 0; ks < 2; ks++)
            qf[nt][ks] = *(const f16x8*)(qtb +
                                         ((size_t)((nq >> 4) + 2 * w + nt) * 2 + ks) * TS +
                                         TILE_OFF(l15, quad));
      }
    }

#pragma unroll
    for (int mt = 0; mt < 4; mt++) {
      int row = 16 * mt + l15;
      pa[mt] = *(const f16x8*)(rbuf + row * 256 + ((192 + quad * 16) ^ ((row & 7) << 4)));
    }
#pragma unroll
    for (int ct = 0; ct < 4; ct++)
#pragma unroll
      for (int mt = 0; mt < 4; mt++)
        oacc[ct][mt] = __builtin_amdgcn_mfma_f32_16x16x32_f16(vfB[1][ct], pa[mt],
                                                              oacc[ct][mt], 0, 0, 0);

    __syncthreads();
  }

  // ---- fused wg projection: part[seg] = wg . (O/N), exclusive f16 stores ----
  f16* obuf = (f16*)sPt;
#pragma unroll
  for (int ct = 0; ct < 4; ct++) {
#pragma unroll
    for (int mt = 0; mt < 4; mt++) {
      f16x4 vals;
#pragma unroll
      for (int r = 0; r < 4; r++)
        vals[r] = (f16)(oacc[ct][mt][r] * (1.0f / (float)N_));
      *(f16x4*)(obuf + (mt * 8 + 2 * w + (ct >> 1)) * TS + l15 * 32 +
                16 * (ct & 1) + 4 * quad) = vals;
    }
  }
  __syncthreads();
  f32x4 accO[4][4];
#pragma unroll
  for (int ot = 0; ot < 4; ot++)
#pragma unroll
    for (int mt = 0; mt < 4; mt++) accO[ot][mt] = (f32x4){0.f, 0.f, 0.f, 0.f};
#pragma unroll
  for (int kt = 0; kt < 8; kt++) {
    f16x8 bO[4];
#pragma unroll
    for (int mt = 0; mt < 4; mt++)
      bO[mt] = *(const f16x8*)(obuf + (mt * 8 + kt) * TS + TILE_OFF(l15, quad));
#pragma unroll
    for (int ot = 0; ot < 4; ot++) {
      f16x8 af = load_wfrag(wg, (4 * w + ot) * 16 + l15, kt * 32 + quad * 8);
#pragma unroll
      for (int mt = 0; mt < 4; mt++)
        accO[ot][mt] = __builtin_amdgcn_mfma_f32_16x16x32_f16(af, bO[mt], accO[ot][mt], 0, 0, 0);
    }
  }
  f16* pb = part + ((size_t)(seg * B_ + b) * C_) * N_;
#pragma unroll
  for (int ot = 0; ot < 4; ot++) {
#pragma unroll
    for (int mt = 0; mt < 4; mt++) {
      int m = m0 + 16 * mt + l15;
#pragma unroll
      for (int r = 0; r < 4; r++) {
        int o = 64 * w + 16 * ot + 4 * quad + r;
        pb[(size_t)o * N_ + m] = (f16)accO[ot][mt][r];
      }
    }
  }
}

// ---------------- K3: out = part0 + part1 + bg ----------------
__global__ __launch_bounds__(256) void combine(const f16* __restrict__ part,
                                               const float* __restrict__ bg,
                                               float* __restrict__ out) {
  size_t i = ((size_t)blockIdx.x * 256 + threadIdx.x) * 8;
  f16x8 p0 = *(const f16x8*)(part + i);
  f16x8 p1 = *(const f16x8*)(part + (size_t)B_ * C_ * N_ + i);
  float bgo = bg[(i >> 12) & 255];
  float4v r0, r1;
#pragma unroll
  for (int j = 0; j < 4; j++) r0[j] = (float)p0[j] + (float)p1[j] + bgo;
#pragma unroll
  for (int j = 0; j < 4; j++) r1[j] = (float)p0[4 + j] + (float)p1[4 + j] + bgo;
  *(float4v*)(out + i) = r0;
  *(float4v*)(out + i + 4) = r1;
}

extern "C" void kernel_launch(void* const* d_in, const int* in_sizes, int n_in,
                              void* d_out, int out_size, void* d_ws, size_t ws_size,
                              hipStream_t stream) {
  const float* x = (const float*)d_in[0];
  const float* wq = (const float*)d_in[1];
  const float* bq = (const float*)d_in[2];
  const float* wk = (const float*)d_in[3];
  const float* bk = (const float*)d_in[4];
  const float* wv = (const float*)d_in[5];
  const float* bv = (const float*)d_in[6];
  const float* wg = (const float*)d_in[7];
  const float* bg = (const float*)d_in[8];
  float* out = (float*)d_out;

  char* ws = (char*)d_ws;
  f16* QTt = (f16*)ws; ws += (size_t)B_ * N_ * CQK * sizeof(f16);   // 2.1 MB
  f16* KTt = (f16*)ws; ws += (size_t)B_ * N_ * CQK * sizeof(f16);   // 2.1 MB
  f16* Vt  = (f16*)ws; ws += (size_t)B_ * C_ * N_ * sizeof(f16);    // 8.4 MB
  f16* PART = (f16*)ws; ws += (size_t)SEG * B_ * C_ * N_ * sizeof(f16);  // 16.8 MB

  proj<<<dim3(N_ / 32, B_), 256, 0, stream>>>(x, wq, wk, wv, bq, bk, bv,
                                              QTt, KTt, Vt);
  attn<<<dim3(SEG * B_, N_ / 64), 256, 0, stream>>>(QTt, KTt, Vt, wg, PART);
  combine<<<dim3(2048), 256, 0, stream>>>(PART, bg, out);
}

// Round 7
// 161.022 us; speedup vs baseline: 1.0787x; 1.0787x over previous
//
#include <hip/hip_runtime.h>

#define B_ 4
#define C_ 256
#define CQK 64
#define N_ 4096
#define SEG 2
#define SEGN (N_ / SEG)    // 2048
#define NB 128
#define ITERS (SEGN / NB)  // 16
#define TS 512             // elements per 16x32 fragment tile (1 KB)

typedef _Float16 f16;
typedef __attribute__((ext_vector_type(8))) _Float16 f16x8;
typedef __attribute__((ext_vector_type(4))) _Float16 f16x4;
typedef __attribute__((ext_vector_type(4))) float f32x4;
typedef __attribute__((ext_vector_type(4))) float float4v;

// Fragment-tiled layouts: matrix [R][K] stored as [R/16][K/32] tiles of
// [16][32] f16; wave fragment load = 64 lanes x 16 B over one 1 KB tile.
#define TILE_OFF(l15, quad) ((l15) * 32 + (quad) * 8)

// ---------------- K0: weights fp32 -> fragment-tiled f16 ----------------
// Kept as a separate tiny kernel: r6 proved inline fp32->f16 conversion on
// the MFMA operand path costs far more than this 3us kernel (attn 62.7->74.5,
// proj v2 regression). Pre-tiled f16 weights are read with single b128 loads.
__global__ __launch_bounds__(256) void prep_w(
    const float* __restrict__ wq, const float* __restrict__ wk,
    const float* __restrict__ wv, const float* __restrict__ wg,
    f16* __restrict__ WQt, f16* __restrict__ WKt, f16* __restrict__ WVt,
    f16* __restrict__ WGt) {
  int chunk = blockIdx.x * 256 + threadIdx.x;
  if (chunk >= 20480) return;
  const float* src;
  f16* dst;
  int lo;
  if (chunk < 2048) { src = wq; dst = WQt; lo = chunk * 8; }
  else if (chunk < 4096) { src = wk; dst = WKt; lo = (chunk - 2048) * 8; }
  else if (chunk < 12288) { src = wv; dst = WVt; lo = (chunk - 4096) * 8; }
  else { src = wg; dst = WGt; lo = (chunk - 12288) * 8; }
  int o = lo >> 8, k = lo & 255;
  f16x8 v;
#pragma unroll
  for (int j = 0; j < 8; j++) v[j] = (f16)src[lo + j];
  *(f16x8*)(dst + ((size_t)(o >> 4) * 8 + (k >> 5)) * TS + (o & 15) * 32 + (k & 31)) = v;
}

// ---------------- K1: fused transpose + Q/K/V projection (v3) ---------------
// v1 was ~75us (inferred: total - attn - combine - prep_w - gaps): 8 barrier
// round-trips, scalar fp32 global loads, 1 block/CU phase serialization.
// v3: grid (N/32, B) = 512 blocks (2/CU), 256 thr. ONE staging pass for the
// whole 256c x 32n chunk as float4-along-n (16 B/lane), padded fp32 LDS
// (stride 265 => <=2-way bank aliasing), ONE repack pass to f16 fragment
// tiles, 2 barriers total. MFMA loop uses pre-tiled f16 weights (b128 loads).
__global__ __launch_bounds__(256) void proj(
    const float* __restrict__ x, const f16* __restrict__ WQt,
    const f16* __restrict__ WKt, const f16* __restrict__ WVt,
    const float* __restrict__ bq, const float* __restrict__ bk,
    const float* __restrict__ bv, f16* __restrict__ QTt, f16* __restrict__ KTt,
    f16* __restrict__ Vt) {
  __shared__ float xs[32][265];   // fp32 transpose stage (32n x 256c), padded
  __shared__ f16 xt[2 * 8 * TS];  // x strip tiled: [nt 2][kt 8][16 n][32 c]
  int n0 = blockIdx.x * 32;
  int b = blockIdx.y;
  int tid = threadIdx.x, lane = tid & 63, w = tid >> 6;  // w 0..3
  int l15 = lane & 15, quad = lane >> 4;
  const float* xb = x + (size_t)b * C_ * N_;

  // stage 1: load 256c x 32n, float4 along n, store transposed into xs
#pragma unroll
  for (int i = 0; i < 8; i++) {
    int c = i * 32 + (tid >> 3);
    int n4 = (tid & 7) * 4;
    float4v f4 = *(const float4v*)(xb + (size_t)c * N_ + n0 + n4);
#pragma unroll
    for (int j = 0; j < 4; j++) xs[n4 + j][c] = f4[j];
  }
  __syncthreads();
  // stage 2: repack to f16 fragment tiles; each wave owns 4 of the 16 tiles
#pragma unroll
  for (int i = 0; i < 4; i++) {
    int t = w + i * 4;  // 0..15
    int nt = t >> 3, kt = t & 7;
    f16x8 v;
#pragma unroll
    for (int j = 0; j < 8; j++)
      v[j] = (f16)xs[nt * 16 + l15][kt * 32 + quad * 8 + j];
    *(f16x8*)(xt + (nt * 8 + kt) * TS + l15 * 32 + quad * 8) = v;
  }
  __syncthreads();

  f32x4 acc[6][2];  // [task j][nt]
#pragma unroll
  for (int j = 0; j < 6; j++)
#pragma unroll
    for (int nt = 0; nt < 2; nt++) acc[j][nt] = (f32x4){0.f, 0.f, 0.f, 0.f};

#pragma unroll
  for (int kt = 0; kt < 8; kt++) {
    f16x8 xf[2];
#pragma unroll
    for (int nt = 0; nt < 2; nt++)
      xf[nt] = *(const f16x8*)(xt + (nt * 8 + kt) * TS + TILE_OFF(l15, quad));
#pragma unroll
    for (int j = 0; j < 6; j++) {
      int g = w * 6 + j;  // wave-uniform, 0..23
      const f16* Wt;
      int ot;
      bool isV = g < 16;
      if (isV) { Wt = WVt; ot = g; }
      else if (g < 20) { Wt = WQt; ot = g - 16; }
      else { Wt = WKt; ot = g - 20; }
      f16x8 wf = *(const f16x8*)(Wt + ((size_t)ot * 8 + kt) * TS + TILE_OFF(l15, quad));
#pragma unroll
      for (int nt = 0; nt < 2; nt++)
        acc[j][nt] = isV
            ? __builtin_amdgcn_mfma_f32_16x16x32_f16(xf[nt], wf, acc[j][nt], 0, 0, 0)
            : __builtin_amdgcn_mfma_f32_16x16x32_f16(wf, xf[nt], acc[j][nt], 0, 0, 0);
    }
  }

  // stores: harness-verified r6 formulas (nt in {0,1}, n0 step 32)
  f16* vbout = Vt + (size_t)b * C_ * N_;
#pragma unroll
  for (int j = 0; j < 6; j++) {
    int g = w * 6 + j;
    if (g < 16) {
      float bvv = bv[16 * g + l15];
#pragma unroll
      for (int nt = 0; nt < 2; nt++) {
        f16x4 vals;
#pragma unroll
        for (int r = 0; r < 4; r++) vals[r] = (f16)(acc[j][nt][r] + bvv);
        *(f16x4*)(vbout + ((size_t)g * 128 + (n0 >> 5)) * TS +
                  l15 * 32 + 16 * nt + 4 * quad) = vals;
      }
    } else {
      int oq = (g < 20) ? (g - 16) : (g - 20);
      const float* bias = (g < 20) ? bq : bk;
      f16* ob = ((g < 20) ? QTt : KTt) + (size_t)b * N_ * CQK;
#pragma unroll
      for (int nt = 0; nt < 2; nt++) {
        f16x4 vals;
#pragma unroll
        for (int r = 0; r < 4; r++)
          vals[r] = (f16)(acc[j][nt][r] + bias[16 * oq + 4 * quad + r]);
        *(f16x4*)(ob + (((size_t)(n0 >> 4) + nt) * 2 + (oq >> 1)) * TS + l15 * 32 +
                  16 * (oq & 1) + 4 * quad) = vals;
      }
    }
  }
}

// ---------------- K2: fused attention + wg proj (r5 pipelined core) ---------
// grid: (8, 64). blockIdx.x = seg*4+b (XCD-pinned via %8), 4 waves.
// Hardened r5 body (62.7us): QK(it+1)+elu interleaved with PV(it), disjoint
// P^T dbuf halves, 1 barrier/iter. f16 pre-tiled WGt in epilogue (r6's inline
// fp32 variant cost +12us).
__global__ __launch_bounds__(256, 2) void attn(const f16* __restrict__ qt,
                                               const f16* __restrict__ kt,
                                               const f16* __restrict__ v,
                                               const f16* __restrict__ WGt,
                                               f16* __restrict__ part) {
  __shared__ __align__(16) f16 sPt[2][64][128];  // P^T dbuf (32 KB); reused as O buf
  int sb = blockIdx.x;
  int seg = sb >> 2;
  int b = sb & 3;
  int m0 = blockIdx.y * 64;
  int tid = threadIdx.x, lane = tid & 63, w = tid >> 6;
  int l15 = lane & 15, quad = lane >> 4;
  const f16* qtb = qt + (size_t)b * N_ * CQK;
  const f16* ktb = kt + (size_t)b * N_ * CQK;
  const f16* vb = v + (size_t)b * C_ * N_;

  f32x4 oacc[4][4];
#pragma unroll
  for (int ct = 0; ct < 4; ct++)
#pragma unroll
    for (int mt = 0; mt < 4; mt++) oacc[ct][mt] = (f32x4){0.f, 0.f, 0.f, 0.f};

  f16x8 kf[4][2];
#pragma unroll
  for (int mt = 0; mt < 4; mt++)
#pragma unroll
    for (int ks = 0; ks < 2; ks++)
      kf[mt][ks] = *(const f16x8*)(ktb + ((size_t)((m0 >> 4) + mt) * 2 + ks) * TS +
                                   TILE_OFF(l15, quad));

  f16x8 qf[2][2];
#pragma unroll
  for (int nt = 0; nt < 2; nt++)
#pragma unroll
    for (int ks = 0; ks < 2; ks++)
      qf[nt][ks] = *(const f16x8*)(qtb +
                                   ((size_t)(((seg * SEGN) >> 4) + 2 * w + nt) * 2 + ks) * TS +
                                   TILE_OFF(l15, quad));

  // ---- prologue: QK(0) -> sPt[0] ----
  {
    char* buf = (char*)sPt[0];
#pragma unroll
    for (int nt = 0; nt < 2; nt++) {
      f32x4 sacc[4];
#pragma unroll
      for (int mt = 0; mt < 4; mt++) sacc[mt] = (f32x4){0.f, 0.f, 0.f, 0.f};
#pragma unroll
      for (int ks = 0; ks < 2; ks++)
#pragma unroll
        for (int mt = 0; mt < 4; mt++)
          sacc[mt] = __builtin_amdgcn_mfma_f32_16x16x32_f16(qf[nt][ks], kf[mt][ks],
                                                            sacc[mt], 0, 0, 0);
#pragma unroll
      for (int mt = 0; mt < 4; mt++) {
        f16x4 p;
#pragma unroll
        for (int r = 0; r < 4; r++) {
          float s = sacc[mt][r];
          p[r] = (f16)(s > 0.0f ? s : (__expf(s) - 1.0f));
        }
        int row = 16 * mt + l15;
        int colb = (64 * w + 32 * nt + 8 * quad) ^ ((row & 7) << 4);
        *(f16x4*)(buf + row * 256 + colb) = p;
      }
    }
  }
  // prefetch qf for it=1 (used by QK(1) inside iter 0)
  {
    int nq = seg * SEGN + NB;
#pragma unroll
    for (int nt = 0; nt < 2; nt++)
#pragma unroll
      for (int ks = 0; ks < 2; ks++)
        qf[nt][ks] = *(const f16x8*)(qtb +
                                     ((size_t)((nq >> 4) + 2 * w + nt) * 2 + ks) * TS +
                                     TILE_OFF(l15, quad));
  }
  __syncthreads();

  for (int it = 0; it < ITERS; it++) {
    int n0 = seg * SEGN + it * NB;
    char* rbuf = (char*)sPt[it & 1];        // P(it), read by PV
    char* wbuf = (char*)sPt[(it + 1) & 1];  // P(it+1), written by QK
    bool hasNext = (it + 1 < ITERS);

    f16x8 vfA[2][4];
#pragma unroll
    for (int ks = 0; ks < 2; ks++)
#pragma unroll
      for (int ct = 0; ct < 4; ct++)
        vfA[ks][ct] = *(const f16x8*)(vb +
                                      ((size_t)(4 * w + ct) * 128 + (n0 >> 5) + ks) * TS +
                                      TILE_OFF(l15, quad));

    // QK(it+1) nt=0 accumulate (interleaves with PV phase 0 below)
    f32x4 s0[4], s1[4];
    if (hasNext) {
#pragma unroll
      for (int mt = 0; mt < 4; mt++) s0[mt] = (f32x4){0.f, 0.f, 0.f, 0.f};
#pragma unroll
      for (int ks = 0; ks < 2; ks++)
#pragma unroll
        for (int mt = 0; mt < 4; mt++)
          s0[mt] = __builtin_amdgcn_mfma_f32_16x16x32_f16(qf[0][ks], kf[mt][ks],
                                                          s0[mt], 0, 0, 0);
    }

    f16x8 pa[4];
#pragma unroll
    for (int mt = 0; mt < 4; mt++) {
      int row = 16 * mt + l15;
      pa[mt] = *(const f16x8*)(rbuf + row * 256 + ((quad * 16) ^ ((row & 7) << 4)));
    }
#pragma unroll
    for (int ct = 0; ct < 4; ct++)
#pragma unroll
      for (int mt = 0; mt < 4; mt++)
        oacc[ct][mt] = __builtin_amdgcn_mfma_f32_16x16x32_f16(vfA[0][ct], pa[mt],
                                                              oacc[ct][mt], 0, 0, 0);

    f16x8 vfB[2][4];
#pragma unroll
    for (int ks = 0; ks < 2; ks++)
#pragma unroll
      for (int ct = 0; ct < 4; ct++)
        vfB[ks][ct] = *(const f16x8*)(vb + ((size_t)(4 * w + ct) * 128 + (n0 >> 5) +
                                            2 + ks) * TS +
                                      TILE_OFF(l15, quad));

    // elu+pack+write for nt=0 (VALU; interleaves with PV MFMA around it)
    if (hasNext) {
#pragma unroll
      for (int mt = 0; mt < 4; mt++) {
        f16x4 p;
#pragma unroll
        for (int r = 0; r < 4; r++) {
          float s = s0[mt][r];
          p[r] = (f16)(s > 0.0f ? s : (__expf(s) - 1.0f));
        }
        int row = 16 * mt + l15;
        int colb = (64 * w + 8 * quad) ^ ((row & 7) << 4);
        *(f16x4*)(wbuf + row * 256 + colb) = p;
      }
    }

#pragma unroll
    for (int mt = 0; mt < 4; mt++) {
      int row = 16 * mt + l15;
      pa[mt] = *(const f16x8*)(rbuf + row * 256 + ((64 + quad * 16) ^ ((row & 7) << 4)));
    }
#pragma unroll
    for (int ct = 0; ct < 4; ct++)
#pragma unroll
      for (int mt = 0; mt < 4; mt++)
        oacc[ct][mt] = __builtin_amdgcn_mfma_f32_16x16x32_f16(vfA[1][ct], pa[mt],
                                                              oacc[ct][mt], 0, 0, 0);

    // QK(it+1) nt=1 accumulate
    if (hasNext) {
#pragma unroll
      for (int mt = 0; mt < 4; mt++) s1[mt] = (f32x4){0.f, 0.f, 0.f, 0.f};
#pragma unroll
      for (int ks = 0; ks < 2; ks++)
#pragma unroll
        for (int mt = 0; mt < 4; mt++)
          s1[mt] = __builtin_amdgcn_mfma_f32_16x16x32_f16(qf[1][ks], kf[mt][ks],
                                                          s1[mt], 0, 0, 0);
    }

#pragma unroll
    for (int mt = 0; mt < 4; mt++) {
      int row = 16 * mt + l15;
      pa[mt] = *(const f16x8*)(rbuf + row * 256 + ((128 + quad * 16) ^ ((row & 7) << 4)));
    }
#pragma unroll
    for (int ct = 0; ct < 4; ct++)
#pragma unroll
      for (int mt = 0; mt < 4; mt++)
        oacc[ct][mt] = __builtin_amdgcn_mfma_f32_16x16x32_f16(vfB[0][ct], pa[mt],
                                                              oacc[ct][mt], 0, 0, 0);

    // elu+pack+write for nt=1, then qf prefetch for it+2
    if (hasNext) {
#pragma unroll
      for (int mt = 0; mt < 4; mt++) {
        f16x4 p;
#pragma unroll
        for (int r = 0; r < 4; r++) {
          float s = s1[mt][r];
          p[r] = (f16)(s > 0.0f ? s : (__expf(s) - 1.0f));
        }
        int row = 16 * mt + l15;
        int colb = (64 * w + 32 + 8 * quad) ^ ((row & 7) << 4);
        *(f16x4*)(wbuf + row * 256 + colb) = p;
      }
      if (it + 2 < ITERS) {
        int nq = seg * SEGN + (it + 2) * NB;
#pragma unroll
        for (int nt = 0; nt < 2; nt++)
#pragma unroll
          for (int ks = 0; ks < 2; ks++)
            qf[nt][ks] = *(const f16x8*)(qtb +
                                         ((size_t)((nq >> 4) + 2 * w + nt) * 2 + ks) * TS +
                                         TILE_OFF(l15, quad));
      }
    }

#pragma unroll
    for (int mt = 0; mt < 4; mt++) {
      int row = 16 * mt + l15;
      pa[mt] = *(const f16x8*)(rbuf + row * 256 + ((192 + quad * 16) ^ ((row & 7) << 4)));
    }
#pragma unroll
    for (int ct = 0; ct < 4; ct++)
#pragma unroll
      for (int mt = 0; mt < 4; mt++)
        oacc[ct][mt] = __builtin_amdgcn_mfma_f32_16x16x32_f16(vfB[1][ct], pa[mt],
                                                              oacc[ct][mt], 0, 0, 0);

    __syncthreads();
  }

  // ---- fused wg projection: part[seg] = wg . (O/N), exclusive f16 stores ----
  f16* obuf = (f16*)sPt;
#pragma unroll
  for (int ct = 0; ct < 4; ct++) {
#pragma unroll
    for (int mt = 0; mt < 4; mt++) {
      f16x4 vals;
#pragma unroll
      for (int r = 0; r < 4; r++)
        vals[r] = (f16)(oacc[ct][mt][r] * (1.0f / (float)N_));
      *(f16x4*)(obuf + (mt * 8 + 2 * w + (ct >> 1)) * TS + l15 * 32 +
                16 * (ct & 1) + 4 * quad) = vals;
    }
  }
  __syncthreads();
  f32x4 accO[4][4];
#pragma unroll
  for (int ot = 0; ot < 4; ot++)
#pragma unroll
    for (int mt = 0; mt < 4; mt++) accO[ot][mt] = (f32x4){0.f, 0.f, 0.f, 0.f};
#pragma unroll
  for (int kt = 0; kt < 8; kt++) {
    f16x8 bO[4];
#pragma unroll
    for (int mt = 0; mt < 4; mt++)
      bO[mt] = *(const f16x8*)(obuf + (mt * 8 + kt) * TS + TILE_OFF(l15, quad));
#pragma unroll
    for (int ot = 0; ot < 4; ot++) {
      f16x8 af = *(const f16x8*)(WGt + ((size_t)(4 * w + ot) * 8 + kt) * TS +
                                 TILE_OFF(l15, quad));
#pragma unroll
      for (int mt = 0; mt < 4; mt++)
        accO[ot][mt] = __builtin_amdgcn_mfma_f32_16x16x32_f16(af, bO[mt], accO[ot][mt], 0, 0, 0);
    }
  }
  f16* pb = part + ((size_t)(seg * B_ + b) * C_) * N_;
#pragma unroll
  for (int ot = 0; ot < 4; ot++) {
#pragma unroll
    for (int mt = 0; mt < 4; mt++) {
      int m = m0 + 16 * mt + l15;
#pragma unroll
      for (int r = 0; r < 4; r++) {
        int o = 64 * w + 16 * ot + 4 * quad + r;
        pb[(size_t)o * N_ + m] = (f16)accO[ot][mt][r];
      }
    }
  }
}

// ---------------- K3: out = part0 + part1 + bg ----------------
__global__ __launch_bounds__(256) void combine(const f16* __restrict__ part,
                                               const float* __restrict__ bg,
                                               float* __restrict__ out) {
  size_t i = ((size_t)blockIdx.x * 256 + threadIdx.x) * 8;
  f16x8 p0 = *(const f16x8*)(part + i);
  f16x8 p1 = *(const f16x8*)(part + (size_t)B_ * C_ * N_ + i);
  float bgo = bg[(i >> 12) & 255];
  float4v r0, r1;
#pragma unroll
  for (int j = 0; j < 4; j++) r0[j] = (float)p0[j] + (float)p1[j] + bgo;
#pragma unroll
  for (int j = 0; j < 4; j++) r1[j] = (float)p0[4 + j] + (float)p1[4 + j] + bgo;
  *(float4v*)(out + i) = r0;
  *(float4v*)(out + i + 4) = r1;
}

extern "C" void kernel_launch(void* const* d_in, const int* in_sizes, int n_in,
                              void* d_out, int out_size, void* d_ws, size_t ws_size,
                              hipStream_t stream) {
  const float* x = (const float*)d_in[0];
  const float* wq = (const float*)d_in[1];
  const float* bq = (const float*)d_in[2];
  const float* wk = (const float*)d_in[3];
  const float* bk = (const float*)d_in[4];
  const float* wv = (const float*)d_in[5];
  const float* bv = (const float*)d_in[6];
  const float* wg = (const float*)d_in[7];
  const float* bg = (const float*)d_in[8];
  float* out = (float*)d_out;

  char* ws = (char*)d_ws;
  f16* QTt = (f16*)ws; ws += (size_t)B_ * N_ * CQK * sizeof(f16);   // 2.1 MB
  f16* KTt = (f16*)ws; ws += (size_t)B_ * N_ * CQK * sizeof(f16);   // 2.1 MB
  f16* Vt  = (f16*)ws; ws += (size_t)B_ * C_ * N_ * sizeof(f16);    // 8.4 MB
  f16* WQt = (f16*)ws; ws += (size_t)CQK * C_ * sizeof(f16);
  f16* WKt = (f16*)ws; ws += (size_t)CQK * C_ * sizeof(f16);
  f16* WVt = (f16*)ws; ws += (size_t)C_ * C_ * sizeof(f16);
  f16* WGt = (f16*)ws; ws += (size_t)C_ * C_ * sizeof(f16);
  f16* PART = (f16*)ws; ws += (size_t)SEG * B_ * C_ * N_ * sizeof(f16);  // 16.8 MB

  prep_w<<<dim3(80), 256, 0, stream>>>(wq, wk, wv, wg, WQt, WKt, WVt, WGt);
  proj<<<dim3(N_ / 32, B_), 256, 0, stream>>>(x, WQt, WKt, WVt, bq, bk, bv,
                                              QTt, KTt, Vt);
  attn<<<dim3(SEG * B_, N_ / 64), 256, 0, stream>>>(QTt, KTt, Vt, WGt, PART);
  combine<<<dim3(2048), 256, 0, stream>>>(PART, bg, out);
}